// Round 8
// baseline (385.131 us; speedup 1.0000x reference)
//
#include <hip/hip_runtime.h>
#include <hip/hip_bf16.h>

// Problem constants
#define Bn 16
#define Cc 512
#define Ss 1024           // H*W tokens per batch
#define HEADS 8
#define DHEAD 64
#define GROUPS 32
#define CPG 16
#define EPSv 1e-5f
#define Mtok (Bn*Ss)      // 16384 token rows
#define PROW 34           // padded image row (32 + halo)
#define PIMG (PROW*PROW)  // 1156 padded tokens per batch

typedef __hip_bfloat16 bf16;
typedef __attribute__((ext_vector_type(8))) short short8;   // MFMA A/B frag (8 bf16)
typedef __attribute__((ext_vector_type(4))) float f32x4;    // MFMA C/D frag

union U4 { uint4 u; bf16 h[8]; };
union B4 { ushort4 u; bf16 h[4]; };

// async global->LDS, 16 B/lane; LDS dest = wave-uniform base + lane*16
__device__ __forceinline__ void stage16(const bf16* g, bf16* l) {
    __builtin_amdgcn_global_load_lds((const __attribute__((address_space(1))) void*)g,
                                     (__attribute__((address_space(3))) void*)l,
                                     16, 0, 0);
}

// ---------------------------------------------------------------------------
// 0) Weight transpose+convert: src f32 [512][512] (k-major) -> dst bf16 [n][k]
// ---------------------------------------------------------------------------
__global__ __launch_bounds__(256) void wtrans(const float* __restrict__ src,
                                              bf16* __restrict__ dst) {
    size_t off = (size_t)blockIdx.y * 262144;
    int t = blockIdx.x * 256 + threadIdx.x;     // 0..32767
    int n = t & 511, k8 = (t >> 9) * 8;
    const float* s = src + off + (size_t)k8 * 512 + n;
    U4 o;
#pragma unroll
    for (int j = 0; j < 8; j++) o.h[j] = __float2bfloat16(s[(size_t)j * 512]);
    *(uint4*)(dst + off + (size_t)n * 512 + k8) = o.u;
}

// ---------------------------------------------------------------------------
// 1) GroupNorm stats
// ---------------------------------------------------------------------------
__global__ __launch_bounds__(256) void gn_stats(const float* __restrict__ x,
                                                float* __restrict__ stats) {
    int bg = blockIdx.x;
    int b = bg >> 5, g = bg & 31;
    int tid = threadIdx.x;
    const size_t base = (size_t)b * Ss * Cc + g * CPG;
    float sum = 0.f, sq = 0.f;
    for (int i = tid; i < 4096; i += 256) {
        int s = i >> 2, c4 = (i & 3) * 4;
        float4 t = *(const float4*)(x + base + (size_t)s * Cc + c4);
        sum += t.x + t.y + t.z + t.w;
        sq  += t.x * t.x + t.y * t.y + t.z * t.z + t.w * t.w;
    }
    __shared__ float s1[4], s2[4];
#pragma unroll
    for (int off = 32; off > 0; off >>= 1) {
        sum += __shfl_down(sum, off);
        sq  += __shfl_down(sq,  off);
    }
    if ((tid & 63) == 0) { s1[tid >> 6] = sum; s2[tid >> 6] = sq; }
    __syncthreads();
    if (tid == 0) {
        float S = s1[0] + s1[1] + s1[2] + s1[3];
        float Q = s2[0] + s2[1] + s2[2] + s2[3];
        float mean = S * (1.f / 16384.f);
        float var  = Q * (1.f / 16384.f) - mean * mean;
        stats[bg * 2 + 0] = mean;
        stats[bg * 2 + 1] = rsqrtf(var + EPSv);
    }
}

// ---------------------------------------------------------------------------
// 2) GroupNorm apply (f32 in, bf16 out)
// ---------------------------------------------------------------------------
__global__ __launch_bounds__(256) void gn_apply(const float* __restrict__ x,
                                                const float* __restrict__ stats,
                                                const float* __restrict__ gamma,
                                                const float* __restrict__ beta,
                                                bf16* __restrict__ xn) {
    size_t i = (size_t)blockIdx.x * 256 + threadIdx.x;
    size_t e = i * 4;
    int c0 = (int)(e & (Cc - 1));
    int token = (int)(e >> 9);
    int b = token >> 10;
    int g = c0 >> 4;
    float mean = stats[(b * 32 + g) * 2 + 0];
    float rstd = stats[(b * 32 + g) * 2 + 1];
    float4 t  = *(const float4*)(x + e);
    float4 gm = *(const float4*)(gamma + c0);
    float4 bt = *(const float4*)(beta + c0);
    B4 o;
    o.h[0] = __float2bfloat16((t.x - mean) * rstd * gm.x + bt.x);
    o.h[1] = __float2bfloat16((t.y - mean) * rstd * gm.y + bt.y);
    o.h[2] = __float2bfloat16((t.z - mean) * rstd * gm.z + bt.z);
    o.h[3] = __float2bfloat16((t.w - mean) * rstd * gm.w + bt.w);
    *(ushort4*)(xn + e) = o.u;
}

// ---------------------------------------------------------------------------
// 2b) Zero the padded-activation border (132 border tokens x 512 ch x 16 b)
// ---------------------------------------------------------------------------
__global__ __launch_bounds__(256) void zero_pad(bf16* __restrict__ Pad) {
    int idx = blockIdx.x * 256 + threadIdx.x;     // exactly 16*132*64
    int b = idx / (132 * 64);
    int rem = idx - b * 132 * 64;
    int t = rem >> 6, seg = rem & 63;
    int r, c;
    if (t < 34)      { r = 0;  c = t; }
    else if (t < 68) { r = 33; c = t - 34; }
    else { int u = t - 68; r = 1 + (u >> 1); c = (u & 1) * 33; }
    uint4 z = {0u, 0u, 0u, 0u};
    *(uint4*)(Pad + ((size_t)b * PIMG + r * PROW + c) * Cc + seg * 8) = z;
}

// ---------------------------------------------------------------------------
// 3) Fused QKV GEMM, m97-style, XCD-swizzled 1-D grid (1536 blocks).
//    Q cols -> qbuf [tok][512], K cols -> kbuf [tok][512],
//    V cols -> vt TRANSPOSED [b][c][tok] (c = v-channel 0..511).
// ---------------------------------------------------------------------------
__global__ __launch_bounds__(256) void gemm_qkv(const bf16* __restrict__ A,
                                                const bf16* __restrict__ Wt,
                                                bf16* __restrict__ qbuf,
                                                bf16* __restrict__ kbuf,
                                                bf16* __restrict__ vt) {
    int id = blockIdx.x;                         // 0..1535
    int m_blk = ((id & 7) << 4) + ((id >> 3) & 15);   // XCD-contiguous M
    int n_blk = id >> 7;                              // 0..11
    int m0 = m_blk * 128, n0 = n_blk * 128;

    __shared__ __align__(16) bf16 As[128][32];
    __shared__ __align__(16) bf16 Bs[128][32];
    int tid = threadIdx.x;
    int wave = tid >> 6, lane = tid & 63;
    int l15 = lane & 15, quad = lane >> 4;
    int wm = wave >> 1, wn = wave & 1;
    int lr = lane >> 2, kseg = (lane & 3) * 8;
    int ar0 = wave * 32 + lr;

    const bf16* ga = A  + (size_t)(m0 + ar0) * Cc + kseg;
    const bf16* gb = Wt + (size_t)(n0 + ar0) * Cc + kseg;
    bf16* la0 = &As[wave * 32][0];
    bf16* la1 = &As[wave * 32 + 16][0];
    bf16* lb0 = &Bs[wave * 32][0];
    bf16* lb1 = &Bs[wave * 32 + 16][0];

    f32x4 acc[4][4] = {};
    for (int k0 = 0; k0 < 512; k0 += 32) {
        __syncthreads();
        stage16(ga + k0,                   la0);
        stage16(ga + k0 + (size_t)16 * Cc, la1);
        stage16(gb + k0,                   lb0);
        stage16(gb + k0 + (size_t)16 * Cc, lb1);
        __syncthreads();
        short8 af[4], bfv[4];
#pragma unroll
        for (int mt = 0; mt < 4; mt++) af[mt]  = *(const short8*)&As[wm * 64 + mt * 16 + l15][quad * 8];
#pragma unroll
        for (int nt = 0; nt < 4; nt++) bfv[nt] = *(const short8*)&Bs[wn * 64 + nt * 16 + l15][quad * 8];
#pragma unroll
        for (int mt = 0; mt < 4; mt++)
#pragma unroll
            for (int nt = 0; nt < 4; nt++)
                acc[mt][nt] = __builtin_amdgcn_mfma_f32_16x16x32_bf16(af[mt], bfv[nt], acc[mt][nt], 0, 0, 0);
    }

    int nbase = n0 + wn * 64;
    if (n0 < 1024) {
        bf16* dst = (n0 < 512) ? qbuf : kbuf;
        int nn = nbase & 511;
#pragma unroll
        for (int mt = 0; mt < 4; mt++)
#pragma unroll
            for (int r = 0; r < 4; r++) {
                size_t row = (size_t)(m0 + wm * 64 + mt * 16 + quad * 4 + r) * Cc + nn + l15;
#pragma unroll
                for (int nt = 0; nt < 4; nt++)
                    dst[row + nt * 16] = __float2bfloat16(acc[mt][nt][r]);
            }
    } else {
        int b = m0 >> 10;
        int tok0 = (m0 & 1023) + wm * 64;
#pragma unroll
        for (int mt = 0; mt < 4; mt++)
#pragma unroll
            for (int nt = 0; nt < 4; nt++) {
                int cch = (nbase - 1024) + nt * 16 + l15;
                B4 o;
#pragma unroll
                for (int r = 0; r < 4; r++) o.h[r] = __float2bfloat16(acc[mt][nt][r]);
                *(ushort4*)(vt + (size_t)b * 524288 + (size_t)cch * 1024
                               + tok0 + mt * 16 + quad * 4) = o.u;
            }
    }
}

// ---------------------------------------------------------------------------
// 4) Flash-style MFMA attention. K staged in 64-key LDS chunks; V read as
//    contiguous B-frags from pre-transposed vt; P via wave-private LDS
//    round-trip. Unnormalized O accumulation + final divide (scores bounded).
// ---------------------------------------------------------------------------
__global__ __launch_bounds__(256) void attention_mfma(const bf16* __restrict__ qbuf,
                                                      const bf16* __restrict__ kbuf,
                                                      const bf16* __restrict__ vt,
                                                      bf16* __restrict__ Pad) {
    int blk = blockIdx.x;
    int qt = blk & 15;
    int bh = blk >> 4;
    int h = bh & (HEADS - 1), b = bh >> 3;
    int tid = threadIdx.x;
    int wave = tid >> 6, lane = tid & 63;
    int l15 = lane & 15, quad = lane >> 4;

    __shared__ __align__(16) bf16 Ks[64][72];
    __shared__ __align__(16) bf16 Ps[4][16][40];

    const bf16* kb = kbuf + (size_t)b * Ss * Cc + h * DHEAD;
    const bf16* vb = vt + (size_t)b * 524288 + (size_t)h * DHEAD * Ss;  // [c][tok]

    int q0 = qt * 64 + wave * 16;
    const bf16* qrow = qbuf + ((size_t)b * Ss + q0 + l15) * Cc + h * DHEAD + quad * 8;
    short8 qf0 = *(const short8*)(qrow);
    short8 qf1 = *(const short8*)(qrow + 32);

    f32x4 oacc[4] = {{0.f,0.f,0.f,0.f},{0.f,0.f,0.f,0.f},{0.f,0.f,0.f,0.f},{0.f,0.f,0.f,0.f}};
    float lsum[4] = {0.f, 0.f, 0.f, 0.f};
    const f32x4 zero4 = {0.f, 0.f, 0.f, 0.f};

    // K staging: t = tid*2+{0,1}: tok = t>>3, 16B seg = (t&7)*8
    int t0 = tid * 2;
    int tokA = t0 >> 3, segA = (t0 & 7) * 8;
    int tokB = tokA,    segB = ((t0 + 1) & 7) * 8;   // t0 even => same tok

    for (int c = 0; c < 16; ++c) {
        __syncthreads();                       // protect Ks reuse
        const bf16* kc = kb + (size_t)(c * 64) * Cc;
        *(uint4*)&Ks[tokA][segA] = *(const uint4*)(kc + (size_t)tokA * Cc + segA);
        *(uint4*)&Ks[tokB][segB] = *(const uint4*)(kc + (size_t)tokB * Cc + segB);
        __syncthreads();
#pragma unroll
        for (int kp = 0; kp < 2; ++kp) {       // two 32-key halves
#pragma unroll
            for (int kh = 0; kh < 2; ++kh) {   // two 16-key score tiles
                int kg = kp * 2 + kh;
                short8 kf0 = *(const short8*)&Ks[kg * 16 + l15][quad * 8];
                short8 kf1 = *(const short8*)&Ks[kg * 16 + l15][32 + quad * 8];
                f32x4 s = __builtin_amdgcn_mfma_f32_16x16x32_bf16(qf0, kf0, zero4, 0, 0, 0);
                s = __builtin_amdgcn_mfma_f32_16x16x32_bf16(qf1, kf1, s, 0, 0, 0);
#pragma unroll
                for (int r = 0; r < 4; r++) {
                    float p = __expf(s[r] * 0.125f);
                    lsum[r] += p;
                    Ps[wave][quad * 4 + r][kh * 16 + l15] = __float2bfloat16(p);
                }
            }
            short8 pf = *(const short8*)&Ps[wave][l15][quad * 8];
            const bf16* vsub = vb + c * 64 + kp * 32 + quad * 8;
#pragma unroll
            for (int dt = 0; dt < 4; dt++) {
                short8 vf = *(const short8*)(vsub + (size_t)(dt * 16 + l15) * Ss);
                oacc[dt] = __builtin_amdgcn_mfma_f32_16x16x32_bf16(pf, vf, oacc[dt], 0, 0, 0);
            }
        }
    }

#pragma unroll
    for (int r = 0; r < 4; r++) {
#pragma unroll
        for (int m = 1; m < 16; m <<= 1) lsum[r] += __shfl_xor(lsum[r], m);
    }
#pragma unroll
    for (int r = 0; r < 4; r++) {
        float inv = 1.f / lsum[r];
        int s = q0 + quad * 4 + r;
        size_t rowoff = ((size_t)(b * PROW + (s >> 5) + 1) * PROW + (s & 31) + 1) * Cc + h * DHEAD;
#pragma unroll
        for (int dt = 0; dt < 4; dt++)
            Pad[rowoff + dt * 16 + l15] = __float2bfloat16(oacc[dt][r] * inv);
    }
}

// ---------------------------------------------------------------------------
// 5) 3x3 conv as m97-style implicit GEMM, XCD-swizzled 1-D grid (512 blocks).
// ---------------------------------------------------------------------------
__global__ __launch_bounds__(256) void conv_mfma(const bf16* __restrict__ Pad,
                                                 const bf16* __restrict__ Wct,
                                                 const float* __restrict__ bias,
                                                 const float* __restrict__ xres,
                                                 float* __restrict__ out) {
    int id = blockIdx.x;                              // 0..511
    int m_blk = ((id & 7) << 4) + ((id >> 3) & 15);   // XCD-contiguous M
    int n_blk = id >> 7;                              // 0..3
    int m0 = m_blk * 128, n0 = n_blk * 128;

    __shared__ __align__(16) bf16 As[128][32];
    __shared__ __align__(16) bf16 Bs[128][32];
    int tid = threadIdx.x;
    int wave = tid >> 6, lane = tid & 63;
    int l15 = lane & 15, quad = lane >> 4;
    int wm = wave >> 1, wn = wave & 1;
    int lr = lane >> 2, kseg = (lane & 3) * 8;
    int ar0 = wave * 32 + lr;

    int tok = m0 + ar0;                  // whole block inside one image (128 | 1024)
    int b = tok >> 10, oh = (tok & 1023) >> 5, ow = tok & 31;
    int prow = (b * PROW + oh + 1) * PROW + ow + 1;   // padded center token

    const bf16* gb = Wct + (size_t)(n0 + ar0) * Cc + kseg;
    bf16* la0 = &As[wave * 32][0];
    bf16* la1 = &As[wave * 32 + 16][0];
    bf16* lb0 = &Bs[wave * 32][0];
    bf16* lb1 = &Bs[wave * 32 + 16][0];

    f32x4 acc[4][4] = {};
    for (int tap = 0; tap < 9; ++tap) {
        int dy = tap / 3 - 1, dx = tap % 3 - 1;
        const bf16* ga = Pad + (size_t)(prow + dy * PROW + dx) * Cc + kseg;
        const bf16* gw = gb + (size_t)tap * (Cc * Cc);
        for (int k0 = 0; k0 < 512; k0 += 32) {
            __syncthreads();
            stage16(ga + k0,                   la0);
            stage16(ga + k0 + (size_t)16 * Cc, la1);   // token +16: same image row
            stage16(gw + k0,                   lb0);
            stage16(gw + k0 + (size_t)16 * Cc, lb1);
            __syncthreads();
            short8 af[4], bfv[4];
#pragma unroll
            for (int mt = 0; mt < 4; mt++) af[mt]  = *(const short8*)&As[wm * 64 + mt * 16 + l15][quad * 8];
#pragma unroll
            for (int nt = 0; nt < 4; nt++) bfv[nt] = *(const short8*)&Bs[wn * 64 + nt * 16 + l15][quad * 8];
#pragma unroll
            for (int mt = 0; mt < 4; mt++)
#pragma unroll
                for (int nt = 0; nt < 4; nt++)
                    acc[mt][nt] = __builtin_amdgcn_mfma_f32_16x16x32_bf16(af[mt], bfv[nt], acc[mt][nt], 0, 0, 0);
        }
    }
#pragma unroll
    for (int mt = 0; mt < 4; mt++)
#pragma unroll
        for (int r = 0; r < 4; r++) {
            size_t row = (size_t)(m0 + wm * 64 + mt * 16 + quad * 4 + r) * Cc + n0 + wn * 64 + l15;
#pragma unroll
            for (int nt = 0; nt < 4; nt++) {
                int n = n0 + wn * 64 + nt * 16 + l15;
                out[row + nt * 16] = acc[mt][nt][r] + bias[n] + xres[row + nt * 16];
            }
        }
}

// ---------------------------------------------------------------------------
extern "C" void kernel_launch(void* const* d_in, const int* in_sizes, int n_in,
                              void* d_out, int out_size, void* d_ws, size_t ws_size,
                              hipStream_t stream) {
    const float* x     = (const float*)d_in[0];
    const float* gamma = (const float*)d_in[1];
    const float* beta  = (const float*)d_in[2];
    const float* wq    = (const float*)d_in[3];
    const float* wk    = (const float*)d_in[4];
    const float* wv    = (const float*)d_in[5];
    const float* convw = (const float*)d_in[6];
    const float* convb = (const float*)d_in[7];
    float* out = (float*)d_out;

    // ws layout (time-multiplexed; peak 71.5 MiB):
    //   [0, 19 MiB)  : pad (written after gemm_qkv) overlaying stats/xn/wt
    //   [19, 35 MiB) : qbuf   [35, 51) : kbuf   [51, 67) : vt   [67, 71.5) : wct
    char* ws = (char*)d_ws;
    bf16*  pad   = (bf16*)ws;
    float* stats = (float*)ws;
    bf16*  xn    = (bf16*)(ws + 4096);
    bf16*  wt    = (bf16*)(ws + 4096 + ((size_t)16 << 20));
    bf16*  qbuf  = (bf16*)(ws + ((size_t)19 << 20));
    bf16*  kbuf  = (bf16*)(ws + ((size_t)35 << 20));
    bf16*  vt    = (bf16*)(ws + ((size_t)51 << 20));
    bf16*  wct   = (bf16*)(ws + ((size_t)67 << 20));

    wtrans<<<dim3(128, 1), 256, 0, stream>>>(wq, wt);
    wtrans<<<dim3(128, 1), 256, 0, stream>>>(wk, wt + 262144);
    wtrans<<<dim3(128, 1), 256, 0, stream>>>(wv, wt + 524288);
    wtrans<<<dim3(128, 9), 256, 0, stream>>>(convw, wct);

    gn_stats<<<dim3(Bn * GROUPS), 256, 0, stream>>>(x, stats);
    gn_apply<<<dim3(Mtok * Cc / (4 * 256)), 256, 0, stream>>>(x, stats, gamma, beta, xn);

    gemm_qkv<<<dim3(1536), 256, 0, stream>>>(xn, wt, qbuf, kbuf, vt);

    zero_pad<<<dim3(528), 256, 0, stream>>>(pad);   // after gemm_qkv: overlays xn/wt
    attention_mfma<<<dim3(Bn * HEADS * (Ss / 64)), 256, 0, stream>>>(qbuf, kbuf, vt, pad);

    conv_mfma<<<dim3(512), 256, 0, stream>>>(pad, wct, convb, x, out);
}